// Round 5
// baseline (282.315 us; speedup 1.0000x reference)
//
#include <hip/hip_runtime.h>
#include <stdint.h>

#define H_DIM 1024
#define B_DIM 16384

typedef unsigned short u16;
typedef short bf16x8 __attribute__((ext_vector_type(8)));
typedef unsigned short ushort8 __attribute__((ext_vector_type(8)));
typedef float f32x4 __attribute__((ext_vector_type(4)));

__device__ __forceinline__ u16 f2bf(float f) {
  union { float f; uint32_t u; } v; v.f = f;
  uint32_t r = v.u + 0x7fffu + ((v.u >> 16) & 1u);
  return (u16)(r >> 16);
}
__device__ __forceinline__ float bf2f(u16 x) {
  union { uint32_t u; float f; } v; v.u = ((uint32_t)x) << 16;
  return v.f;
}

#define GLDS16(gsrc, ldst)                                                                 \
  __builtin_amdgcn_global_load_lds((const __attribute__((address_space(1))) void*)(gsrc),  \
                                   (__attribute__((address_space(3))) void*)(ldst), 16, 0, 0)

// 4 weight matrices -> bf16 (256 blocks each) + rtau = 1/tau (block 1024).
__global__ __launch_bounds__(256) void cvt4_f32_bf16(const float* __restrict__ a0,
                                                     const float* __restrict__ a1,
                                                     const float* __restrict__ a2,
                                                     const float* __restrict__ a3,
                                                     u16* __restrict__ o0, u16* __restrict__ o1,
                                                     u16* __restrict__ o2, u16* __restrict__ o3,
                                                     const float* __restrict__ tau,
                                                     float* __restrict__ rtau) {
  if (blockIdx.x >= 1024) {
    for (int i = threadIdx.x; i < H_DIM; i += 256) rtau[i] = 1.0f / tau[i];
    return;
  }
  const int which = blockIdx.x >> 8;
  const float* in = which == 0 ? a0 : which == 1 ? a1 : which == 2 ? a2 : a3;
  u16* out = which == 0 ? o0 : which == 1 ? o1 : which == 2 ? o2 : o3;
  const int n4 = (H_DIM * H_DIM) / 4;
  int i = (blockIdx.x & 255) * 256 + threadIdx.x;
  const float4* in4 = (const float4*)in;
  ushort4* out4 = (ushort4*)out;
  for (; i < n4; i += 256 * 256) {
    float4 v = in4[i];
    ushort4 o;
    o.x = f2bf(v.x); o.y = f2bf(v.y); o.z = f2bf(v.z); o.w = f2bf(v.w);
    out4[i] = o;
  }
}

// ---------------- bf16-A GEMM (unchanged from r4, verified) ----------------
template <int MODE>  // 3: stage+vmcnt(8); 2: vmcnt(4); 1: vmcnt(0); 0: none
__device__ __forceinline__ void subtile_step(u16* shp, int slot, int slot3, int aoff, int boff,
                                             int wv, const u16*& pA0, const u16*& pA1,
                                             const u16*& pB0, const u16*& pB1,
                                             f32x4 (&acc)[8][4]) {
  const u16* Ab = shp + slot * 16384 + aoff;
  const u16* Bb = shp + slot * 16384 + 8192 + boff;
  bf16x8 aF[8], bF[4];
#pragma unroll
  for (int i = 0; i < 4; ++i) aF[i] = *(const bf16x8*)(Ab + i * 512);
#pragma unroll
  for (int i = 0; i < 4; ++i) bF[i] = *(const bf16x8*)(Bb + i * 512);
#pragma unroll
  for (int i = 4; i < 8; ++i) aF[i] = *(const bf16x8*)(Ab + i * 512);
  if (MODE == 3) {
    u16* da = shp + slot3 * 16384 + wv * 1024;
    GLDS16(pA0, da); GLDS16(pA1, da + 512);
    u16* db = shp + slot3 * 16384 + 8192 + wv * 1024;
    GLDS16(pB0, db); GLDS16(pB1, db + 512);
    pA0 += 32; pA1 += 32; pB0 += 32; pB1 += 32;
  }
  __builtin_amdgcn_s_setprio(1);
#pragma unroll
  for (int mf = 0; mf < 4; ++mf)
#pragma unroll
    for (int nf = 0; nf < 4; ++nf)
      acc[mf][nf] = __builtin_amdgcn_mfma_f32_16x16x32_bf16(aF[mf], bF[nf], acc[mf][nf], 0, 0, 0);
#pragma unroll
  for (int mf = 4; mf < 8; ++mf)
#pragma unroll
    for (int nf = 0; nf < 4; ++nf)
      acc[mf][nf] = __builtin_amdgcn_mfma_f32_16x16x32_bf16(aF[mf], bF[nf], acc[mf][nf], 0, 0, 0);
  __builtin_amdgcn_s_setprio(0);
  if (MODE == 3) asm volatile("s_waitcnt vmcnt(8)" ::: "memory");
  if (MODE == 2) asm volatile("s_waitcnt vmcnt(4)" ::: "memory");
  if (MODE == 1) asm volatile("s_waitcnt vmcnt(0)" ::: "memory");
  __builtin_amdgcn_s_barrier();
}

template <bool RELU, bool HASBIAS, typename OUT>
__global__ __launch_bounds__(512, 2) void gemm256(const u16* __restrict__ A,
                                                  const u16* __restrict__ W,
                                                  const float* __restrict__ bias,
                                                  OUT* __restrict__ C) {
  extern __shared__ u16 sh[];
  const int t = threadIdx.x;
  const int wv = t >> 6, l = t & 63;
  const int wm = wv >> 2, wn = wv & 3;
  const int l15 = l & 15, lg = l >> 4;

  const int bid = blockIdx.x;
  const int logical = (bid & 7) * 32 + (bid >> 3);
  const int m0 = (logical >> 2) * 256;
  const int n0 = (logical & 3) * 256;

  const int koff = (lg ^ ((l15 >> 1) & 3)) * 8;
  const int aoff = (wm * 128 + l15) * 32 + koff;
  const int boff = (wn * 64 + l15) * 32 + koff;

  const int rowst = wv * 32 + (l >> 2);
  const int ksl = ((l & 3) ^ ((l >> 3) & 3)) * 8;
  const u16* pA0 = A + (size_t)(m0 + rowst) * H_DIM + ksl;
  const u16* pA1 = pA0 + 16 * H_DIM;
  const u16* pB0 = W + (size_t)(n0 + rowst) * H_DIM + ksl;
  const u16* pB1 = pB0 + 16 * H_DIM;

  f32x4 acc[8][4] = {};

#pragma unroll
  for (int s = 0; s < 3; ++s) {
    u16* da = sh + s * 16384 + wv * 1024;
    GLDS16(pA0, da); GLDS16(pA1, da + 512);
    u16* db = sh + s * 16384 + 8192 + wv * 1024;
    GLDS16(pB0, db); GLDS16(pB1, db + 512);
    pA0 += 32; pA1 += 32; pB0 += 32; pB1 += 32;
  }
  asm volatile("s_waitcnt vmcnt(8)" ::: "memory");
  __builtin_amdgcn_s_barrier();

  for (int s = 0; s < 29; ++s)
    subtile_step<3>(sh, s & 3, (s + 3) & 3, aoff, boff, wv, pA0, pA1, pB0, pB1, acc);
  subtile_step<2>(sh, 1, 0, aoff, boff, wv, pA0, pA1, pB0, pB1, acc);
  subtile_step<1>(sh, 2, 0, aoff, boff, wv, pA0, pA1, pB0, pB1, acc);
  subtile_step<0>(sh, 3, 0, aoff, boff, wv, pA0, pA1, pB0, pB1, acc);

  float bv[4];
#pragma unroll
  for (int nf = 0; nf < 4; ++nf)
    bv[nf] = HASBIAS ? bias[n0 + wn * 64 + nf * 16 + l15] : 0.0f;
#pragma unroll
  for (int mf = 0; mf < 8; ++mf) {
#pragma unroll
    for (int nf = 0; nf < 4; ++nf) {
      const int col = n0 + wn * 64 + nf * 16 + l15;
#pragma unroll
      for (int j = 0; j < 4; ++j) {
        const int row = m0 + wm * 128 + mf * 16 + lg * 4 + j;
        float v = acc[mf][nf][j] + bv[nf];
        if (RELU) v = fmaxf(v, 0.0f);
        if constexpr (sizeof(OUT) == 2)
          C[(size_t)row * H_DIM + col] = (OUT)f2bf(v);
        else
          C[(size_t)row * H_DIM + col] = v;
      }
    }
  }
}

// ---------------- fp32-A GEMM: in-kernel cvt, reg-staged A (T14), gload_lds B ----------------
// A-loads at subtile s (K=(s+4)*32) -> reg set (s+2)&3, ds_written at s+2 into slot (s+4)&3,
// read at s+4 (2-subtile latency cover). B gload_lds at s -> slot (s+3)&3 (3-subtile cover).
// End-of-subtile vmcnt(12) retires B(s-2) under ANY compiler ordering of plain A-loads
// (min ops-after-B(s-2) = 6(s-1)+6(s) = 12). lgkmcnt(0) before barrier publishes ds_writes.
template <int P, bool DO_A, bool DO_B, bool DO_W, int VE>
__device__ __forceinline__ void step_f32a(u16* sh, int aoff, int boff, int wv, int l,
                                          const float*& gA, const u16*& pB0, const u16*& pB1,
                                          f32x4 (&ra)[4][4], f32x4 (&acc)[8][4]) {
  constexpr int WSLOT = (P + 2) & 3;
  constexpr int BSLOT = (P + 3) & 3;
  const u16* Ab = sh + P * 16384 + aoff;
  const u16* Bb = sh + P * 16384 + 8192 + boff;
  bf16x8 aF[8], bF[4];
#pragma unroll
  for (int i = 0; i < 4; ++i) aF[i] = *(const bf16x8*)(Ab + i * 512);
#pragma unroll
  for (int i = 0; i < 4; ++i) bF[i] = *(const bf16x8*)(Bb + i * 512);
#pragma unroll
  for (int i = 4; i < 8; ++i) aF[i] = *(const bf16x8*)(Ab + i * 512);
  if constexpr (DO_W) {
    ushort8 w0, w1;
#pragma unroll
    for (int j = 0; j < 4; ++j) {
      w0[j] = f2bf(ra[P][0][j]);
      w0[4 + j] = f2bf(ra[P][1][j]);
      w1[j] = f2bf(ra[P][2][j]);
      w1[4 + j] = f2bf(ra[P][3][j]);
    }
    u16* dw = sh + WSLOT * 16384 + wv * 1024 + l * 8;
    *(ushort8*)dw = w0;
    *(ushort8*)(dw + 512) = w1;
  }
  if constexpr (DO_A) {
    ra[WSLOT][0] = *(const f32x4*)(gA);
    ra[WSLOT][1] = *(const f32x4*)(gA + 4);
    ra[WSLOT][2] = *(const f32x4*)(gA + 16 * H_DIM);
    ra[WSLOT][3] = *(const f32x4*)(gA + 16 * H_DIM + 4);
    gA += 32;
  }
  if constexpr (DO_B) {
    u16* db = sh + BSLOT * 16384 + 8192 + wv * 1024;
    GLDS16(pB0, db);
    GLDS16(pB1, db + 512);
    pB0 += 32;
    pB1 += 32;
  }
  __builtin_amdgcn_s_setprio(1);
#pragma unroll
  for (int mf = 0; mf < 4; ++mf)
#pragma unroll
    for (int nf = 0; nf < 4; ++nf)
      acc[mf][nf] = __builtin_amdgcn_mfma_f32_16x16x32_bf16(aF[mf], bF[nf], acc[mf][nf], 0, 0, 0);
#pragma unroll
  for (int mf = 4; mf < 8; ++mf)
#pragma unroll
    for (int nf = 0; nf < 4; ++nf)
      acc[mf][nf] = __builtin_amdgcn_mfma_f32_16x16x32_bf16(aF[mf], bF[nf], acc[mf][nf], 0, 0, 0);
  __builtin_amdgcn_s_setprio(0);
  if constexpr (VE == 12) asm volatile("s_waitcnt vmcnt(12)" ::: "memory");
  if constexpr (VE == 8) asm volatile("s_waitcnt vmcnt(8)" ::: "memory");
  if constexpr (VE == 2) asm volatile("s_waitcnt vmcnt(2)" ::: "memory");
  if constexpr (VE == 0) asm volatile("s_waitcnt vmcnt(0)" ::: "memory");
  asm volatile("s_waitcnt lgkmcnt(0)" ::: "memory");
  __builtin_amdgcn_s_barrier();
}

template <bool RELU, bool HASBIAS>
__global__ __launch_bounds__(512, 1) void gemm256_f32a(const float* __restrict__ A,
                                                       const u16* __restrict__ W,
                                                       const float* __restrict__ bias,
                                                       u16* __restrict__ C) {
  extern __shared__ u16 sh[];
  const int t = threadIdx.x;
  const int wv = t >> 6, l = t & 63;
  const int wm = wv >> 2, wn = wv & 3;
  const int l15 = l & 15, lg = l >> 4;

  const int bid = blockIdx.x;
  const int logical = (bid & 7) * 32 + (bid >> 3);
  const int m0 = (logical >> 2) * 256;
  const int n0 = (logical & 3) * 256;

  const int koff = (lg ^ ((l15 >> 1) & 3)) * 8;
  const int aoff = (wm * 128 + l15) * 32 + koff;
  const int boff = (wn * 64 + l15) * 32 + koff;

  const int rowst = wv * 32 + (l >> 2);
  const int ksl = ((l & 3) ^ ((l >> 3) & 3)) * 8;
  const float* gA = A + (size_t)(m0 + rowst) * H_DIM + ksl;
  const u16* pB0 = W + (size_t)(n0 + rowst) * H_DIM + ksl;
  const u16* pB1 = pB0 + 16 * H_DIM;

  f32x4 acc[8][4] = {};
  f32x4 ra[4][4];

  // Prologue: A-regs for slots 0..3 (K=0,32,64,96); B gload slots 0..2; write slots 0,1.
  f32x4 t0[4], t1v[4];
  t0[0] = *(const f32x4*)(gA); t0[1] = *(const f32x4*)(gA + 4);
  t0[2] = *(const f32x4*)(gA + 16 * H_DIM); t0[3] = *(const f32x4*)(gA + 16 * H_DIM + 4);
  gA += 32;
  t1v[0] = *(const f32x4*)(gA); t1v[1] = *(const f32x4*)(gA + 4);
  t1v[2] = *(const f32x4*)(gA + 16 * H_DIM); t1v[3] = *(const f32x4*)(gA + 16 * H_DIM + 4);
  gA += 32;
  ra[0][0] = *(const f32x4*)(gA); ra[0][1] = *(const f32x4*)(gA + 4);
  ra[0][2] = *(const f32x4*)(gA + 16 * H_DIM); ra[0][3] = *(const f32x4*)(gA + 16 * H_DIM + 4);
  gA += 32;
  ra[1][0] = *(const f32x4*)(gA); ra[1][1] = *(const f32x4*)(gA + 4);
  ra[1][2] = *(const f32x4*)(gA + 16 * H_DIM); ra[1][3] = *(const f32x4*)(gA + 16 * H_DIM + 4);
  gA += 32;
#pragma unroll
  for (int s = 0; s < 3; ++s) {
    u16* db = sh + s * 16384 + 8192 + wv * 1024;
    GLDS16(pB0, db); GLDS16(pB1, db + 512);
    pB0 += 32; pB1 += 32;
  }
  {
    ushort8 w0, w1;
#pragma unroll
    for (int j = 0; j < 4; ++j) {
      w0[j] = f2bf(t0[0][j]); w0[4 + j] = f2bf(t0[1][j]);
      w1[j] = f2bf(t0[2][j]); w1[4 + j] = f2bf(t0[3][j]);
    }
    u16* dw = sh + wv * 1024 + l * 8;
    *(ushort8*)dw = w0; *(ushort8*)(dw + 512) = w1;
#pragma unroll
    for (int j = 0; j < 4; ++j) {
      w0[j] = f2bf(t1v[0][j]); w0[4 + j] = f2bf(t1v[1][j]);
      w1[j] = f2bf(t1v[2][j]); w1[4 + j] = f2bf(t1v[3][j]);
    }
    dw = sh + 16384 + wv * 1024 + l * 8;
    *(ushort8*)dw = w0; *(ushort8*)(dw + 512) = w1;
  }
  asm volatile("s_waitcnt vmcnt(0)" ::: "memory");
  asm volatile("s_waitcnt lgkmcnt(0)" ::: "memory");
  __builtin_amdgcn_s_barrier();

  // s = 0..27 full; tail s = 28..31.
  for (int su = 0; su < 7; ++su) {
    step_f32a<0, true, true, true, 12>(sh, aoff, boff, wv, l, gA, pB0, pB1, ra, acc);
    step_f32a<1, true, true, true, 12>(sh, aoff, boff, wv, l, gA, pB0, pB1, ra, acc);
    step_f32a<2, true, true, true, 12>(sh, aoff, boff, wv, l, gA, pB0, pB1, ra, acc);
    step_f32a<3, true, true, true, 12>(sh, aoff, boff, wv, l, gA, pB0, pB1, ra, acc);
  }
  step_f32a<0, false, true, true, 8>(sh, aoff, boff, wv, l, gA, pB0, pB1, ra, acc);
  step_f32a<1, false, false, true, 2>(sh, aoff, boff, wv, l, gA, pB0, pB1, ra, acc);
  step_f32a<2, false, false, false, 0>(sh, aoff, boff, wv, l, gA, pB0, pB1, ra, acc);
  step_f32a<3, false, false, false, -1>(sh, aoff, boff, wv, l, gA, pB0, pB1, ra, acc);

  float bv[4];
#pragma unroll
  for (int nf = 0; nf < 4; ++nf)
    bv[nf] = HASBIAS ? bias[n0 + wn * 64 + nf * 16 + l15] : 0.0f;
#pragma unroll
  for (int mf = 0; mf < 8; ++mf) {
#pragma unroll
    for (int nf = 0; nf < 4; ++nf) {
      const int col = n0 + wn * 64 + nf * 16 + l15;
#pragma unroll
      for (int j = 0; j < 4; ++j) {
        const int row = m0 + wm * 128 + mf * 16 + lg * 4 + j;
        float v = acc[mf][nf][j] + bv[nf];
        if (RELU) v = fmaxf(v, 0.0f);
        C[(size_t)row * H_DIM + col] = f2bf(v);
      }
    }
  }
}

// ---------------- fused liquid-neuron update + LayerNorm ----------------
__global__ __launch_bounds__(256) void liquid_ln(const float* __restrict__ h,
                                                 const u16* __restrict__ pa,
                                                 const u16* __restrict__ ev,
                                                 const float* __restrict__ bias,
                                                 const float* __restrict__ rtau,
                                                 const float* __restrict__ decay,
                                                 const float* __restrict__ lnw,
                                                 const float* __restrict__ lnb,
                                                 float* __restrict__ out) {
  const int wv = threadIdx.x >> 6, l = threadIdx.x & 63;
  const int row = blockIdx.x * 4 + wv;
  const size_t rb = (size_t)row * H_DIM;

  float d[16];
  float s = 0.f, ss = 0.f;
#pragma unroll
  for (int c = 0; c < 2; ++c) {
    const int col = c * 512 + l * 8;
    float h8[8], b8[8], r8[8], dc8[8];
    *(float4*)h8 = *(const float4*)(h + rb + col);
    *(float4*)(h8 + 4) = *(const float4*)(h + rb + col + 4);
    *(float4*)b8 = *(const float4*)(bias + col);
    *(float4*)(b8 + 4) = *(const float4*)(bias + col + 4);
    *(float4*)r8 = *(const float4*)(rtau + col);
    *(float4*)(r8 + 4) = *(const float4*)(rtau + col + 4);
    *(float4*)dc8 = *(const float4*)(decay + col);
    *(float4*)(dc8 + 4) = *(const float4*)(decay + col + 4);
    ushort8 pv = *(const ushort8*)(pa + rb + col);
    ushort8 evv = *(const ushort8*)(ev + rb + col);
#pragma unroll
    for (int j = 0; j < 8; ++j) {
      const float p = bf2f(pv[j]);
      const float e = bf2f(evv[j]);
      const float num = fmaf(-dc8[j], h8[j], fmaf(1.0f + p, e, b8[j]));
      const float val = num * (1.0f + __expf(-p)) * r8[j];
      d[c * 8 + j] = val;
      s += val;
      ss += val * val;
    }
  }
#pragma unroll
  for (int off = 32; off; off >>= 1) {
    s += __shfl_xor(s, off);
    ss += __shfl_xor(ss, off);
  }
  const float mu = s * (1.0f / H_DIM);
  const float var = ss * (1.0f / H_DIM) - mu * mu;
  const float rstd = rsqrtf(var + 1e-5f);

#pragma unroll
  for (int c = 0; c < 2; ++c) {
    const int col = c * 512 + l * 8;
    float w8[8], lb8[8], o[8];
    *(float4*)w8 = *(const float4*)(lnw + col);
    *(float4*)(w8 + 4) = *(const float4*)(lnw + col + 4);
    *(float4*)lb8 = *(const float4*)(lnb + col);
    *(float4*)(lb8 + 4) = *(const float4*)(lnb + col + 4);
#pragma unroll
    for (int j = 0; j < 8; ++j) o[j] = fmaf((d[c * 8 + j] - mu) * rstd, w8[j], lb8[j]);
    *(float4*)(out + rb + col) = *(float4*)o;
    *(float4*)(out + rb + col + 4) = *(float4*)(o + 4);
  }
}

extern "C" void kernel_launch(void* const* d_in, const int* in_sizes, int n_in,
                              void* d_out, int out_size, void* d_ws, size_t ws_size,
                              hipStream_t stream) {
  // setup_inputs order: t, h, e, W_rec, bias, tau, decay, ln_w, ln_b,
  //                     ce_w1, ce_b1, ce_w2, ce_b2, pm_w, pm_b
  const float* h = (const float*)d_in[1];
  const float* e = (const float*)d_in[2];
  const float* Wrec = (const float*)d_in[3];
  const float* bias = (const float*)d_in[4];
  const float* tau = (const float*)d_in[5];
  const float* decay = (const float*)d_in[6];
  const float* lnw = (const float*)d_in[7];
  const float* lnb = (const float*)d_in[8];
  const float* ce_w1 = (const float*)d_in[9];
  const float* ce_b1 = (const float*)d_in[10];
  const float* ce_w2 = (const float*)d_in[11];
  const float* ce_b2 = (const float*)d_in[12];
  const float* pm_w = (const float*)d_in[13];
  const float* pm_b = (const float*)d_in[14];
  float* out = (float*)d_out;

  char* ws = (char*)d_ws;
  const size_t MB = 1024 * 1024;
  u16* w1b = (u16*)(ws + 0 * MB);
  u16* w2b = (u16*)(ws + 2 * MB);
  u16* w3b = (u16*)(ws + 4 * MB);
  u16* w4b = (u16*)(ws + 6 * MB);
  u16* t1 = (u16*)(ws + 8 * MB);
  u16* ctx = (u16*)(ws + 40 * MB);
  u16* pab = (u16*)(ws + 72 * MB);
  u16* evb = (u16*)(ws + 104 * MB);
  float* rtau = (float*)(ws + 136 * MB);

  cvt4_f32_bf16<<<1025, 256, 0, stream>>>(ce_w1, ce_w2, pm_w, Wrec, w1b, w2b, w3b, w4b, tau, rtau);

  const int LDS_BYTES = 131072;
  hipFuncSetAttribute((const void*)gemm256_f32a<true, true>,
                      hipFuncAttributeMaxDynamicSharedMemorySize, LDS_BYTES);
  hipFuncSetAttribute((const void*)gemm256_f32a<false, false>,
                      hipFuncAttributeMaxDynamicSharedMemorySize, LDS_BYTES);
  hipFuncSetAttribute((const void*)gemm256<false, true, u16>,
                      hipFuncAttributeMaxDynamicSharedMemorySize, LDS_BYTES);

  const int NWG = (B_DIM / 256) * (H_DIM / 256);  // 256 blocks = 1 per CU
  gemm256_f32a<true, true><<<NWG, 512, LDS_BYTES, stream>>>(h, w1b, ce_b1, t1);
  gemm256<false, true, u16><<<NWG, 512, LDS_BYTES, stream>>>(t1, w2b, ce_b2, ctx);
  gemm256<false, true, u16><<<NWG, 512, LDS_BYTES, stream>>>(ctx, w3b, pm_b, pab);
  gemm256_f32a<false, false><<<NWG, 512, LDS_BYTES, stream>>>(e, w4b, nullptr, evb);

  liquid_ln<<<B_DIM / 4, 256, 0, stream>>>(h, pab, evb, bias, rtau, decay, lnw, lnb, out);
}

// Round 6
// 215.302 us; speedup vs baseline: 1.3113x; 1.3113x over previous
//
#include <hip/hip_runtime.h>
#include <stdint.h>

#define H_DIM 1024
#define B_DIM 16384

typedef unsigned short u16;
typedef short bf16x8 __attribute__((ext_vector_type(8)));
typedef unsigned short ushort8 __attribute__((ext_vector_type(8)));
typedef float f32x4 __attribute__((ext_vector_type(4)));

__device__ __forceinline__ u16 f2bf(float f) {
  union { float f; uint32_t u; } v; v.f = f;
  uint32_t r = v.u + 0x7fffu + ((v.u >> 16) & 1u);
  return (u16)(r >> 16);
}
__device__ __forceinline__ float bf2f(u16 x) {
  union { uint32_t u; float f; } v; v.u = ((uint32_t)x) << 16;
  return v.f;
}

#define GLDS16(gsrc, ldst)                                                                 \
  __builtin_amdgcn_global_load_lds((const __attribute__((address_space(1))) void*)(gsrc),  \
                                   (__attribute__((address_space(3))) void*)(ldst), 16, 0, 0)

// ---------------- merged conversion kernel: h, e, 4 weights, rtau in ONE dispatch ----------
// Blocks 0..2047: h (B*H).  2048..4095: e.  4096..5119: weights (256 blocks each).
// Block 5120: rtau = 1/tau.  4 independent float4 conversions in flight per thread (ILP fix:
// r4's cvt2 ran at 3.6 TB/s with 8 VGPRs = 1 outstanding load).
__global__ __launch_bounds__(256) void cvt_all(const float* __restrict__ h,
                                               const float* __restrict__ e,
                                               const float* __restrict__ w0f,
                                               const float* __restrict__ w1f,
                                               const float* __restrict__ w2f,
                                               const float* __restrict__ w3f,
                                               u16* __restrict__ hb, u16* __restrict__ eb,
                                               u16* __restrict__ o0, u16* __restrict__ o1,
                                               u16* __restrict__ o2, u16* __restrict__ o3,
                                               const float* __restrict__ tau,
                                               float* __restrict__ rtau) {
  const int b = blockIdx.x;
  if (b >= 5120) {
    for (int i = threadIdx.x; i < H_DIM; i += 256) rtau[i] = 1.0f / tau[i];
    return;
  }
  if (b < 4096) {
    // h or e: n4 = 4,194,304 float4; 524288 threads per tensor; 8 iters = 2 groups of 4.
    const float4* in4 = (const float4*)(b < 2048 ? h : e);
    ushort4* out4 = (ushort4*)(b < 2048 ? hb : eb);
    const int base = (b & 2047) * 256 + threadIdx.x;
#pragma unroll
    for (int g = 0; g < 2; ++g) {
      float4 v[4];
#pragma unroll
      for (int u = 0; u < 4; ++u) v[u] = in4[base + (g * 4 + u) * 524288];
#pragma unroll
      for (int u = 0; u < 4; ++u) {
        ushort4 o;
        o.x = f2bf(v[u].x); o.y = f2bf(v[u].y); o.z = f2bf(v[u].z); o.w = f2bf(v[u].w);
        out4[base + (g * 4 + u) * 524288] = o;
      }
    }
  } else {
    // weights: n4 = 262144 float4; 65536 threads per tensor; exactly 4 iters, one group.
    const int which = (b - 4096) >> 8;
    const float4* in4 =
        (const float4*)(which == 0 ? w0f : which == 1 ? w1f : which == 2 ? w2f : w3f);
    ushort4* out4 = (ushort4*)(which == 0 ? o0 : which == 1 ? o1 : which == 2 ? o2 : o3);
    const int base = ((b - 4096) & 255) * 256 + threadIdx.x;
    float4 v[4];
#pragma unroll
    for (int u = 0; u < 4; ++u) v[u] = in4[base + u * 65536];
#pragma unroll
    for (int u = 0; u < 4; ++u) {
      ushort4 o;
      o.x = f2bf(v[u].x); o.y = f2bf(v[u].y); o.z = f2bf(v[u].z); o.w = f2bf(v[u].w);
      out4[base + u * 65536] = o;
    }
  }
}

// ---------------- 256x256-tile deep-pipelined GEMM (r4-verified, ~30 us each) ----------------
// 512 threads = 8 waves (2M x 4N); per-wave output 128x64 = acc[8][4].
// LDS ring: 4 slots x (A 256x32 + B 256x32) bf16 = 128 KiB, 1 block/CU.
// ONE barrier per subtile: {12 ds_read, stage s+3 (4 gloads), setprio1, 32 MFMA
//   (compiler interleaves lgkm waits), setprio0, vmcnt(8), barrier}.
// Swizzle: LDS[row][slot16] holds k-slot slot16^((row>>1)&3); same XOR on read addr;
// gload_lds dest linear, source pre-swizzled (rule 21).
template <int MODE>  // 3: stage+vmcnt(8); 2: vmcnt(4); 1: vmcnt(0); 0: none
__device__ __forceinline__ void subtile_step(u16* shp, int slot, int slot3, int aoff, int boff,
                                             int wv, const u16*& pA0, const u16*& pA1,
                                             const u16*& pB0, const u16*& pB1,
                                             f32x4 (&acc)[8][4]) {
  const u16* Ab = shp + slot * 16384 + aoff;
  const u16* Bb = shp + slot * 16384 + 8192 + boff;
  bf16x8 aF[8], bF[4];
#pragma unroll
  for (int i = 0; i < 4; ++i) aF[i] = *(const bf16x8*)(Ab + i * 512);
#pragma unroll
  for (int i = 0; i < 4; ++i) bF[i] = *(const bf16x8*)(Bb + i * 512);
#pragma unroll
  for (int i = 4; i < 8; ++i) aF[i] = *(const bf16x8*)(Ab + i * 512);
  if (MODE == 3) {
    u16* da = shp + slot3 * 16384 + wv * 1024;
    GLDS16(pA0, da); GLDS16(pA1, da + 512);
    u16* db = shp + slot3 * 16384 + 8192 + wv * 1024;
    GLDS16(pB0, db); GLDS16(pB1, db + 512);
    pA0 += 32; pA1 += 32; pB0 += 32; pB1 += 32;
  }
  __builtin_amdgcn_s_setprio(1);
#pragma unroll
  for (int mf = 0; mf < 4; ++mf)
#pragma unroll
    for (int nf = 0; nf < 4; ++nf)
      acc[mf][nf] = __builtin_amdgcn_mfma_f32_16x16x32_bf16(aF[mf], bF[nf], acc[mf][nf], 0, 0, 0);
#pragma unroll
  for (int mf = 4; mf < 8; ++mf)
#pragma unroll
    for (int nf = 0; nf < 4; ++nf)
      acc[mf][nf] = __builtin_amdgcn_mfma_f32_16x16x32_bf16(aF[mf], bF[nf], acc[mf][nf], 0, 0, 0);
  __builtin_amdgcn_s_setprio(0);
  if (MODE == 3) asm volatile("s_waitcnt vmcnt(8)" ::: "memory");
  if (MODE == 2) asm volatile("s_waitcnt vmcnt(4)" ::: "memory");
  if (MODE == 1) asm volatile("s_waitcnt vmcnt(0)" ::: "memory");
  __builtin_amdgcn_s_barrier();
}

template <bool RELU, bool HASBIAS, typename OUT>
__global__ __launch_bounds__(512, 2) void gemm256(const u16* __restrict__ A,
                                                  const u16* __restrict__ W,
                                                  const float* __restrict__ bias,
                                                  OUT* __restrict__ C) {
  extern __shared__ u16 sh[];
  const int t = threadIdx.x;
  const int wv = t >> 6, l = t & 63;
  const int wm = wv >> 2, wn = wv & 3;
  const int l15 = l & 15, lg = l >> 4;

  const int bid = blockIdx.x;
  const int logical = (bid & 7) * 32 + (bid >> 3);
  const int m0 = (logical >> 2) * 256;
  const int n0 = (logical & 3) * 256;

  const int koff = (lg ^ ((l15 >> 1) & 3)) * 8;
  const int aoff = (wm * 128 + l15) * 32 + koff;
  const int boff = (wn * 64 + l15) * 32 + koff;

  const int rowst = wv * 32 + (l >> 2);
  const int ksl = ((l & 3) ^ ((l >> 3) & 3)) * 8;
  const u16* pA0 = A + (size_t)(m0 + rowst) * H_DIM + ksl;
  const u16* pA1 = pA0 + 16 * H_DIM;
  const u16* pB0 = W + (size_t)(n0 + rowst) * H_DIM + ksl;
  const u16* pB1 = pB0 + 16 * H_DIM;

  f32x4 acc[8][4] = {};

#pragma unroll
  for (int s = 0; s < 3; ++s) {
    u16* da = sh + s * 16384 + wv * 1024;
    GLDS16(pA0, da); GLDS16(pA1, da + 512);
    u16* db = sh + s * 16384 + 8192 + wv * 1024;
    GLDS16(pB0, db); GLDS16(pB1, db + 512);
    pA0 += 32; pA1 += 32; pB0 += 32; pB1 += 32;
  }
  asm volatile("s_waitcnt vmcnt(8)" ::: "memory");
  __builtin_amdgcn_s_barrier();

  for (int s = 0; s < 29; ++s)
    subtile_step<3>(sh, s & 3, (s + 3) & 3, aoff, boff, wv, pA0, pA1, pB0, pB1, acc);
  subtile_step<2>(sh, 1, 0, aoff, boff, wv, pA0, pA1, pB0, pB1, acc);
  subtile_step<1>(sh, 2, 0, aoff, boff, wv, pA0, pA1, pB0, pB1, acc);
  subtile_step<0>(sh, 3, 0, aoff, boff, wv, pA0, pA1, pB0, pB1, acc);

  float bv[4];
#pragma unroll
  for (int nf = 0; nf < 4; ++nf)
    bv[nf] = HASBIAS ? bias[n0 + wn * 64 + nf * 16 + l15] : 0.0f;
#pragma unroll
  for (int mf = 0; mf < 8; ++mf) {
#pragma unroll
    for (int nf = 0; nf < 4; ++nf) {
      const int col = n0 + wn * 64 + nf * 16 + l15;
#pragma unroll
      for (int j = 0; j < 4; ++j) {
        const int row = m0 + wm * 128 + mf * 16 + lg * 4 + j;
        float v = acc[mf][nf][j] + bv[nf];
        if (RELU) v = fmaxf(v, 0.0f);
        if constexpr (sizeof(OUT) == 2)
          C[(size_t)row * H_DIM + col] = (OUT)f2bf(v);
        else
          C[(size_t)row * H_DIM + col] = v;
      }
    }
  }
}

// ---------------- fused liquid-neuron update + LayerNorm ----------------
// One WAVE per row; lane l, chunk c -> cols [c*512 + l*8, +8) (coalesced 16B bf16 loads).
// h read as bf16 (hbf, already computed) -> 160 MB total traffic.
// No divides: val = num * (1 + exp(-pa)) * rtau.
__global__ __launch_bounds__(256) void liquid_ln(const u16* __restrict__ hb,
                                                 const u16* __restrict__ pa,
                                                 const u16* __restrict__ ev,
                                                 const float* __restrict__ bias,
                                                 const float* __restrict__ rtau,
                                                 const float* __restrict__ decay,
                                                 const float* __restrict__ lnw,
                                                 const float* __restrict__ lnb,
                                                 float* __restrict__ out) {
  const int wv = threadIdx.x >> 6, l = threadIdx.x & 63;
  const int row = blockIdx.x * 4 + wv;
  const size_t rb = (size_t)row * H_DIM;

  float d[16];
  float s = 0.f, ss = 0.f;
#pragma unroll
  for (int c = 0; c < 2; ++c) {
    const int col = c * 512 + l * 8;
    float b8[8], r8[8], dc8[8];
    *(float4*)b8 = *(const float4*)(bias + col);
    *(float4*)(b8 + 4) = *(const float4*)(bias + col + 4);
    *(float4*)r8 = *(const float4*)(rtau + col);
    *(float4*)(r8 + 4) = *(const float4*)(rtau + col + 4);
    *(float4*)dc8 = *(const float4*)(decay + col);
    *(float4*)(dc8 + 4) = *(const float4*)(decay + col + 4);
    ushort8 hv = *(const ushort8*)(hb + rb + col);
    ushort8 pv = *(const ushort8*)(pa + rb + col);
    ushort8 evv = *(const ushort8*)(ev + rb + col);
#pragma unroll
    for (int j = 0; j < 8; ++j) {
      const float hf = bf2f(hv[j]);
      const float p = bf2f(pv[j]);
      const float e = bf2f(evv[j]);
      const float num = fmaf(-dc8[j], hf, fmaf(1.0f + p, e, b8[j]));
      const float val = num * (1.0f + __expf(-p)) * r8[j];
      d[c * 8 + j] = val;
      s += val;
      ss += val * val;
    }
  }
#pragma unroll
  for (int off = 32; off; off >>= 1) {
    s += __shfl_xor(s, off);
    ss += __shfl_xor(ss, off);
  }
  const float mu = s * (1.0f / H_DIM);
  const float var = ss * (1.0f / H_DIM) - mu * mu;
  const float rstd = rsqrtf(var + 1e-5f);

#pragma unroll
  for (int c = 0; c < 2; ++c) {
    const int col = c * 512 + l * 8;
    float w8[8], lb8[8], o[8];
    *(float4*)w8 = *(const float4*)(lnw + col);
    *(float4*)(w8 + 4) = *(const float4*)(lnw + col + 4);
    *(float4*)lb8 = *(const float4*)(lnb + col);
    *(float4*)(lb8 + 4) = *(const float4*)(lnb + col + 4);
#pragma unroll
    for (int j = 0; j < 8; ++j) o[j] = fmaf((d[c * 8 + j] - mu) * rstd, w8[j], lb8[j]);
    *(float4*)(out + rb + col) = *(float4*)o;
    *(float4*)(out + rb + col + 4) = *(float4*)(o + 4);
  }
}

extern "C" void kernel_launch(void* const* d_in, const int* in_sizes, int n_in,
                              void* d_out, int out_size, void* d_ws, size_t ws_size,
                              hipStream_t stream) {
  // setup_inputs order: t, h, e, W_rec, bias, tau, decay, ln_w, ln_b,
  //                     ce_w1, ce_b1, ce_w2, ce_b2, pm_w, pm_b
  const float* h = (const float*)d_in[1];
  const float* e = (const float*)d_in[2];
  const float* Wrec = (const float*)d_in[3];
  const float* bias = (const float*)d_in[4];
  const float* tau = (const float*)d_in[5];
  const float* decay = (const float*)d_in[6];
  const float* lnw = (const float*)d_in[7];
  const float* lnb = (const float*)d_in[8];
  const float* ce_w1 = (const float*)d_in[9];
  const float* ce_b1 = (const float*)d_in[10];
  const float* ce_w2 = (const float*)d_in[11];
  const float* ce_b2 = (const float*)d_in[12];
  const float* pm_w = (const float*)d_in[13];
  const float* pm_b = (const float*)d_in[14];
  float* out = (float*)d_out;

  char* ws = (char*)d_ws;
  const size_t MB = 1024 * 1024;
  // Layout (stream-ordered lifetimes):
  //  [0,2) w1 | [2,4) w2 | [4,6) w3 | [6,8) w4 | [8,40) hbf (live until ln)
  //  [40,72) ebf (dead after G4) | [72,104) t1 (dead after G2) -> pab (G3 output)
  //  [104,136) ctx (dead after G3) -> evb (G4 output) | [136,137) rtau
  u16* w1b = (u16*)(ws + 0 * MB);
  u16* w2b = (u16*)(ws + 2 * MB);
  u16* w3b = (u16*)(ws + 4 * MB);
  u16* w4b = (u16*)(ws + 6 * MB);
  u16* hbf = (u16*)(ws + 8 * MB);
  u16* ebf = (u16*)(ws + 40 * MB);
  u16* t1 = (u16*)(ws + 72 * MB);
  u16* ctx = (u16*)(ws + 104 * MB);
  u16* pab = (u16*)(ws + 72 * MB);   // over t1 (dead after G2)
  u16* evb = (u16*)(ws + 104 * MB);  // over ctx (dead after G3)
  float* rtau = (float*)(ws + 136 * MB);

  cvt_all<<<5121, 256, 0, stream>>>(h, e, ce_w1, ce_w2, pm_w, Wrec, hbf, ebf, w1b, w2b, w3b, w4b,
                                    tau, rtau);

  const int LDS_BYTES = 131072;
  hipFuncSetAttribute((const void*)gemm256<true, true, u16>,
                      hipFuncAttributeMaxDynamicSharedMemorySize, LDS_BYTES);
  hipFuncSetAttribute((const void*)gemm256<false, true, u16>,
                      hipFuncAttributeMaxDynamicSharedMemorySize, LDS_BYTES);
  hipFuncSetAttribute((const void*)gemm256<false, false, u16>,
                      hipFuncAttributeMaxDynamicSharedMemorySize, LDS_BYTES);

  const int NWG = (B_DIM / 256) * (H_DIM / 256);  // 256 blocks = 1 per CU
  gemm256<true, true, u16><<<NWG, 512, LDS_BYTES, stream>>>(hbf, w1b, ce_b1, t1);
  gemm256<false, true, u16><<<NWG, 512, LDS_BYTES, stream>>>(t1, w2b, ce_b2, ctx);
  gemm256<false, true, u16><<<NWG, 512, LDS_BYTES, stream>>>(ctx, w3b, pm_b, pab);
  gemm256<false, false, u16><<<NWG, 512, LDS_BYTES, stream>>>(ebf, w4b, nullptr, evb);

  liquid_ln<<<B_DIM / 4, 256, 0, stream>>>(hbf, pab, evb, bias, rtau, decay, lnw, lnb, out);
}